// Round 14
// baseline (662.108 us; speedup 1.0000x reference)
//
#include <hip/hip_runtime.h>

// ---------------------------------------------------------------------------
// HybridSAGEClassifier: 3x SAGEConv(mean) + BN + ReLU, then fusion MLP.
// R1: project-first (mean(x[src])@Wl == mean((x@Wl)[src])).
// R2: scatter-atomics -> CSR + register gather.
// R3: single-block scan -> 3-stage parallel scan.
// R4: register-blocked GEMM + norm/ReLU fused into consumers.
// R5: one-pass ELL; bf16 gather table.
// R6: MFMA 16x16x32_bf16, bf16x3 split (~fp32 accuracy).
// R7: gather: 4-node interleaved chains, 8-edge uint4 requests; Yr bf16.
// R8: ell_fill -> 16 temporally-sharded dst ranges (L2-resident writes).
// R9 FAILED: block-centric per-lane gather. R8 layout is right for this.
// R10: R8 gather + T in bf16 + XBF16 GEMM staging.
// R11: branch-free gather (sentinel row); bn_finalize fused into consumers.
// R12: gemm sX LDS had zero reuse -> direct global A-loads; ELL stride 48.
// R13 FAILED: column-phase gather doubled FETCH (72->138MB) -> fetch
//      granularity is 128B = one full row; R12's full-row gather is already
//      line-optimal. Reverted.
// R14: gather occupancy was capped by VGPR=68 (>64 boundary halves waves/CU)
//      -> bias folded into GEMM epilogue (kills bc[8]), BN stats accumulated
//      in per-wave-owned LDS slots (kills ssum/ssq[16]),
//      __launch_bounds__(256,8) pins VGPR<=64 -> 2x wave residency for the
//      latency-bound gather.
// ---------------------------------------------------------------------------

typedef __attribute__((ext_vector_type(8))) short bf16x8;
typedef __attribute__((ext_vector_type(4))) float f32x4;

#define ELLS 48  // ELL row stride

__device__ __forceinline__ ushort f2bf(float f) {
  unsigned u = __float_as_uint(f);
  return (ushort)((u + 0x7fff + ((u >> 16) & 1)) >> 16);  // RNE
}
__device__ __forceinline__ float bf2f(ushort h) {
  return __uint_as_float((unsigned)h << 16);
}
__device__ __forceinline__ void unpack8(uint4 v, float* f) {
  f[0] = __uint_as_float(v.x << 16);
  f[1] = __uint_as_float(v.x & 0xffff0000u);
  f[2] = __uint_as_float(v.y << 16);
  f[3] = __uint_as_float(v.y & 0xffff0000u);
  f[4] = __uint_as_float(v.z << 16);
  f[5] = __uint_as_float(v.z & 0xffff0000u);
  f[6] = __uint_as_float(v.w << 16);
  f[7] = __uint_as_float(v.w & 0xffff0000u);
}

// ---- ELL init: fill with sentinel row index n ------------------------------

__global__ __launch_bounds__(256) void ell_init(int4* __restrict__ ell,
                                                int val, int cnt4) {
  int i = blockIdx.x * 256 + threadIdx.x;
  if (i < cnt4) ell[i] = make_int4(val, val, val, val);
}

// ---- ELL build: temporally sharded scatter (R8) ----------------------------

__global__ __launch_bounds__(256) void ell_fill_sharded(
    const int* __restrict__ ei, int* __restrict__ deg, int* __restrict__ ell,
    int E, int n, int bps) {
  const int shard = blockIdx.x / bps;      // 0..15
  const int bib = blockIdx.x % bps;        // block-in-shard
  const int chunk = n >> 4;                // n/16
  const int lo = shard * chunk;
  const int hi = (shard == 15) ? n : lo + chunk;
  for (int e = bib * 256 + threadIdx.x; e < E; e += bps * 256) {
    int d = ei[E + e];
    if (d >= lo && d < hi) {
      int s = ei[e];
      int pos = atomicAdd(&deg[d], 1);
      if (pos < ELLS) ell[(size_t)d * ELLS + pos] = s;
    }
  }
}

// ---- W prep: combined (Wl|Wr) -> col-major bf16 hi/lo ----------------------

__global__ void prep_w(const float* __restrict__ Wl,
                       const float* __restrict__ Wr, ushort* __restrict__ Whi,
                       ushort* __restrict__ Wlo, int din) {
  int i = blockIdx.x * blockDim.x + threadIdx.x;
  if (i >= 128 * din) return;
  int col = i / din, k = i % din;
  float v = (col < 64) ? Wl[(size_t)k * 64 + col]
                       : Wr[(size_t)k * 64 + (col - 64)];
  ushort h = f2bf(v);
  Whi[i] = h;
  Wlo[i] = f2bf(v - bf2f(h));
}

// ---- MFMA dual GEMM (direct global A-loads; bias folded into Yr) -----------
// [Ybf | Yrbf+bias] = f(X) @ [Wl | Wr]; f = BN(stats,g,be)+ReLU or identity.
template <int DIN, bool NORM, bool XBF16>
__global__ __launch_bounds__(256) void gemm_mfma(
    const void* __restrict__ Xv, const float* __restrict__ stats,
    const float* __restrict__ g, const float* __restrict__ be,
    const float* __restrict__ bias, const ushort* __restrict__ Whi,
    const ushort* __restrict__ Wlo, ushort* __restrict__ Ybf,
    ushort* __restrict__ Yrbf, int n) {
  constexpr int WS = 40;
  __shared__ ushort sW[2 * 128 * WS];
  __shared__ float sSS[128];
  __shared__ float sB[64];
  const int tid = threadIdx.x;
  const int w = tid >> 6;
  const int lane = tid & 63;
  const int m = lane & 15;
  const int quad = lane >> 4;
  const int row0 = blockIdx.x * 64;

  if (tid < 64) {
    sB[tid] = bias[tid];
    if (NORM) {
      float invn = 1.0f / (float)n;
      float mu = stats[tid] * invn;
      float var = fmaf(-mu, mu, stats[64 + tid] * invn);
      float sc = g[tid] * rsqrtf(var + 1e-5f);
      sSS[tid] = sc;
      sSS[64 + tid] = fmaf(-mu, sc, be[tid]);
    }
  }

  const int arow = min(row0 + w * 16 + m, n - 1);

  f32x4 acc[8];
#pragma unroll
  for (int t = 0; t < 8; t++) acc[t] = (f32x4){0.f, 0.f, 0.f, 0.f};

  for (int kc = 0; kc < DIN; kc += 32) {
    __syncthreads();  // prev sW reads done / sSS+sB ready (first iter)
    for (int i = tid; i < 512; i += 256) {
      int col = i >> 2;
      int k = (i & 3) * 8;
      *reinterpret_cast<uint4*>(sW + col * WS + k) =
          *reinterpret_cast<const uint4*>(Whi + (size_t)col * DIN + kc + k);
      *reinterpret_cast<uint4*>(sW + 128 * WS + col * WS + k) =
          *reinterpret_cast<const uint4*>(Wlo + (size_t)col * DIN + kc + k);
    }
    __syncthreads();

    const int kb = kc + quad * 8;
    float av[8];
    if (XBF16) {
      const ushort* X = (const ushort*)Xv;
      uint4 v = *reinterpret_cast<const uint4*>(X + (size_t)arow * DIN + kb);
      unpack8(v, av);
    } else {
      const float* X = (const float*)Xv;
      const float* ap = X + (size_t)arow * DIN + kb;
      float4 a0 = *reinterpret_cast<const float4*>(ap);
      float4 a1 = *reinterpret_cast<const float4*>(ap + 4);
      av[0] = a0.x; av[1] = a0.y; av[2] = a0.z; av[3] = a0.w;
      av[4] = a1.x; av[5] = a1.y; av[6] = a1.z; av[7] = a1.w;
    }
    if (NORM) {
#pragma unroll
      for (int j = 0; j < 8; j++)
        av[j] = fmaxf(fmaf(av[j], sSS[kb + j], sSS[64 + kb + j]), 0.f);
    }
    bf16x8 Ahi, Alo;
#pragma unroll
    for (int j = 0; j < 8; j++) {
      ushort h = f2bf(av[j]);
      Ahi[j] = (short)h;
      Alo[j] = (short)f2bf(av[j] - bf2f(h));
    }
#pragma unroll
    for (int t = 0; t < 8; t++) {
      bf16x8 Bhi =
          *reinterpret_cast<const bf16x8*>(sW + (t * 16 + m) * WS + quad * 8);
      bf16x8 Blo = *reinterpret_cast<const bf16x8*>(sW + 128 * WS +
                                                    (t * 16 + m) * WS +
                                                    quad * 8);
      acc[t] = __builtin_amdgcn_mfma_f32_16x16x32_bf16(Ahi, Bhi, acc[t], 0, 0, 0);
      acc[t] = __builtin_amdgcn_mfma_f32_16x16x32_bf16(Ahi, Blo, acc[t], 0, 0, 0);
      acc[t] = __builtin_amdgcn_mfma_f32_16x16x32_bf16(Alo, Bhi, acc[t], 0, 0, 0);
    }
  }

#pragma unroll
  for (int t = 0; t < 8; t++) {
    int col = t * 16 + m;
#pragma unroll
    for (int r = 0; r < 4; r++) {
      int grow = row0 + w * 16 + quad * 4 + r;
      if (grow < n) {
        float v = acc[t][r];
        if (t < 4) {
          Ybf[(size_t)grow * 64 + col] = f2bf(v);
        } else {
          Yrbf[(size_t)grow * 64 + (col - 64)] = f2bf(v + sB[col - 64]);
        }
      }
    }
  }
}

// ---- ELL gather (R12 structure; stats in LDS; VGPR<=64) --------------------
// grp=lane>>3 picks one of 8 edge slots; sub=lane&7 picks a col octet
// (uint4 = 8 bf16; 8 lanes cover the full 128B row = one fetch line).
// Branch-free via sentinel row n (zeroed). Bias pre-folded into Yrbf.
// BN stats accumulated into per-wave-owned LDS slots at finalize.
__global__ __launch_bounds__(256, 8) void gather_combine(
    const ushort* __restrict__ Ybf, const ushort* __restrict__ Yrbf,
    const int* __restrict__ ell, const int* __restrict__ deg,
    ushort* __restrict__ Tbf, float* __restrict__ stats, int n) {
  __shared__ float rS[4][64];
  __shared__ float rQ[4][64];
  const int lane = threadIdx.x & 63;
  const int w = threadIdx.x >> 6;
  const int grp = lane >> 3;
  const int sub = lane & 7;
  const int wid = blockIdx.x * 4 + w;
  const int nw = gridDim.x * 4;
  if (lane < 8) {
#pragma unroll
    for (int c = 0; c < 8; c++) {
      rS[w][sub * 8 + c] = 0.f;
      rQ[w][sub * 8 + c] = 0.f;
    }
  }

  for (int base = wid * 4; base < n; base += nw * 4) {
    int4 dg4 = *reinterpret_cast<const int4*>(deg + base);  // deg padded +4
    int dg[4] = {dg4.x, dg4.y, dg4.z, dg4.w};
    int mx = 0;
#pragma unroll
    for (int j = 0; j < 4; j++) mx = max(mx, min(dg[j], ELLS));
    float a[4][8];
#pragma unroll
    for (int j = 0; j < 4; j++)
#pragma unroll
      for (int c = 0; c < 8; c++) a[j][c] = 0.f;

    for (int e0 = 0; e0 < mx; e0 += 8) {
      int idx = e0 + grp;
      int s0 = ell[(size_t)(base + 0) * ELLS + idx];
      int s1 = ell[(size_t)(base + 1) * ELLS + idx];
      int s2 = ell[(size_t)(base + 2) * ELLS + idx];
      int s3 = ell[(size_t)(base + 3) * ELLS + idx];
      uint4 v0 = *reinterpret_cast<const uint4*>(Ybf + (size_t)s0 * 64 + sub * 8);
      uint4 v1 = *reinterpret_cast<const uint4*>(Ybf + (size_t)s1 * 64 + sub * 8);
      uint4 v2 = *reinterpret_cast<const uint4*>(Ybf + (size_t)s2 * 64 + sub * 8);
      uint4 v3 = *reinterpret_cast<const uint4*>(Ybf + (size_t)s3 * 64 + sub * 8);
      float f[8];
      unpack8(v0, f);
#pragma unroll
      for (int c = 0; c < 8; c++) a[0][c] += f[c];
      unpack8(v1, f);
#pragma unroll
      for (int c = 0; c < 8; c++) a[1][c] += f[c];
      unpack8(v2, f);
#pragma unroll
      for (int c = 0; c < 8; c++) a[2][c] += f[c];
      unpack8(v3, f);
#pragma unroll
      for (int c = 0; c < 8; c++) a[3][c] += f[c];
    }
#pragma unroll
    for (int mmask = 8; mmask <= 32; mmask <<= 1)
#pragma unroll
      for (int j = 0; j < 4; j++)
#pragma unroll
        for (int c = 0; c < 8; c++)
          a[j][c] += __shfl_xor(a[j][c], mmask, 64);

    if (lane < 8) {  // grp == 0: finalize; lane sub owns cols sub*8..+7
#pragma unroll
      for (int j = 0; j < 4; j++) {
        int node = base + j;
        if (node >= n) continue;
        float iv = 1.0f / (float)max(dg[j], 1);
        uint4 yrv =
            *reinterpret_cast<const uint4*>(Yrbf + (size_t)node * 64 + sub * 8);
        float yr[8];
        unpack8(yrv, yr);
        float t[8];
#pragma unroll
        for (int c = 0; c < 8; c++) {
          t[c] = fmaf(a[j][c], iv, yr[c]);  // bias already in Yrbf
          rS[w][sub * 8 + c] += t[c];
          rQ[w][sub * 8 + c] += t[c] * t[c];
        }
        uint4 o;
        o.x = (uint)f2bf(t[0]) | ((uint)f2bf(t[1]) << 16);
        o.y = (uint)f2bf(t[2]) | ((uint)f2bf(t[3]) << 16);
        o.z = (uint)f2bf(t[4]) | ((uint)f2bf(t[5]) << 16);
        o.w = (uint)f2bf(t[6]) | ((uint)f2bf(t[7]) << 16);
        *reinterpret_cast<uint4*>(Tbf + (size_t)node * 64 + sub * 8) = o;
      }
    }
  }
  __syncthreads();
  if (threadIdx.x < 64) {
    int tc = threadIdx.x;
    float s = rS[0][tc] + rS[1][tc] + rS[2][tc] + rS[3][tc];
    float qq = rQ[0][tc] + rQ[1][tc] + rQ[2][tc] + rQ[3][tc];
    atomicAdd(&stats[tc], s);
    atomicAdd(&stats[64 + tc], qq);
  }
}

// ---- fusion MLP: layer-3 BN (from raw stats) + ReLU fused, T in bf16 -------

__global__ __launch_bounds__(256) void fusion_fused(
    const ushort* __restrict__ Tbf, const float* __restrict__ stats,
    const float* __restrict__ g, const float* __restrict__ be,
    const float* __restrict__ xgb, const float* __restrict__ Wf1,
    const float* __restrict__ bf1, const float* __restrict__ Wf2,
    const float* __restrict__ bf2, float* __restrict__ out, int n) {
  __shared__ float sH[64 * 64];
  __shared__ float sW1[65 * 64];
  __shared__ float sW2[64];
  __shared__ float sSS[128];
  const int tid = threadIdx.x;
  const int c = tid & 63;
  const int w = tid >> 6;
  const int row0 = blockIdx.x * 64;
  if (tid < 64) {
    float invn = 1.0f / (float)n;
    float mu = stats[tid] * invn;
    float var = fmaf(-mu, mu, stats[64 + tid] * invn);
    float sc = g[tid] * rsqrtf(var + 1e-5f);
    sSS[tid] = sc;
    sSS[64 + tid] = fmaf(-mu, sc, be[tid]);
  }
  for (int i = tid; i < 65 * 64; i += 256) sW1[i] = Wf1[i];
  if (tid < 64) sW2[tid] = Wf2[tid];
  __syncthreads();
  for (int i = tid; i < 512; i += 256) {
    int r = i >> 3;
    int k = (i & 7) * 8;
    int row = min(row0 + r, n - 1);
    uint4 v = *reinterpret_cast<const uint4*>(Tbf + (size_t)row * 64 + k);
    float f[8];
    unpack8(v, f);
#pragma unroll
    for (int j = 0; j < 8; j++)
      f[j] = fmaxf(fmaf(f[j], sSS[k + j], sSS[64 + k + j]), 0.f);
    *reinterpret_cast<float4*>(sH + r * 64 + k) =
        make_float4(f[0], f[1], f[2], f[3]);
    *reinterpret_cast<float4*>(sH + r * 64 + k + 4) =
        make_float4(f[4], f[5], f[6], f[7]);
  }
  __syncthreads();
  const float b1v = bf1[c];
  const float wx = sW1[64 * 64 + c];
  const float w2v = sW2[c];
  const float b2v = bf2[0];
  float acc[16];
#pragma unroll
  for (int r = 0; r < 16; r++) acc[r] = b1v;
  for (int kk = 0; kk < 64; kk += 4) {
    float4 hv[16];
#pragma unroll
    for (int r = 0; r < 16; r++)
      hv[r] = *reinterpret_cast<const float4*>(sH + (w * 16 + r) * 64 + kk);
    float w0 = sW1[(kk + 0) * 64 + c];
    float w1 = sW1[(kk + 1) * 64 + c];
    float w2 = sW1[(kk + 2) * 64 + c];
    float w3 = sW1[(kk + 3) * 64 + c];
#pragma unroll
    for (int r = 0; r < 16; r++) {
      acc[r] = fmaf(hv[r].x, w0, acc[r]);
      acc[r] = fmaf(hv[r].y, w1, acc[r]);
      acc[r] = fmaf(hv[r].z, w2, acc[r]);
      acc[r] = fmaf(hv[r].w, w3, acc[r]);
    }
  }
#pragma unroll
  for (int r = 0; r < 16; r++) {
    int row = row0 + w * 16 + r;
    float xv = (row < n) ? xgb[row] : 0.f;
    float z = fmaxf(fmaf(xv, wx, acc[r]), 0.f) * w2v;
#pragma unroll
    for (int off = 32; off > 0; off >>= 1) z += __shfl_xor(z, off, 64);
    if (row < n && c == 0) out[row] = z + b2v;
  }
}

// ---- launch ----------------------------------------------------------------

extern "C" void kernel_launch(void* const* d_in, const int* in_sizes, int n_in,
                              void* d_out, int out_size, void* d_ws,
                              size_t ws_size, hipStream_t stream) {
  const float* x = (const float*)d_in[0];
  const int* ei = (const int*)d_in[1];
  const float* xgb = (const float*)d_in[2];
  const float* W1l = (const float*)d_in[3];
  const float* b1 = (const float*)d_in[4];
  const float* W1r = (const float*)d_in[5];
  const float* g1 = (const float*)d_in[6];
  const float* be1 = (const float*)d_in[7];
  const float* W2l = (const float*)d_in[8];
  const float* b2 = (const float*)d_in[9];
  const float* W2r = (const float*)d_in[10];
  const float* g2 = (const float*)d_in[11];
  const float* be2 = (const float*)d_in[12];
  const float* W3l = (const float*)d_in[13];
  const float* b3 = (const float*)d_in[14];
  const float* W3r = (const float*)d_in[15];
  const float* g3 = (const float*)d_in[16];
  const float* be3 = (const float*)d_in[17];
  const float* Wf1 = (const float*)d_in[18];
  const float* bf1 = (const float*)d_in[19];
  const float* Wf2 = (const float*)d_in[20];
  const float* bf2 = (const float*)d_in[21];
  float* out = (float*)d_out;

  const int n = in_sizes[2];      // 100000
  const int E = in_sizes[1] / 2;  // 1200000

  char* w = (char*)d_ws;
  auto alloc = [&](size_t bytes) {
    void* p = (void*)w;
    w += (bytes + 255) & ~(size_t)255;
    return p;
  };
  int* deg = (int*)alloc((size_t)(n + 4) * 4);           // +4 pad for int4
  int* ell = (int*)alloc((size_t)(n + 4) * ELLS * 4);    // +4 pad rows
  ushort* Ybf = (ushort*)alloc((size_t)(n + 1) * 64 * 2);  // +1 zero row
  ushort* Yrbf = (ushort*)alloc((size_t)n * 64 * 2);
  ushort* Tbf = (ushort*)alloc((size_t)n * 64 * 2);
  ushort* Whi1 = (ushort*)alloc(128 * 128 * 2);
  ushort* Wlo1 = (ushort*)alloc(128 * 128 * 2);
  ushort* Whi2 = (ushort*)alloc(128 * 64 * 2);
  ushort* Wlo2 = (ushort*)alloc(128 * 64 * 2);
  ushort* Whi3 = (ushort*)alloc(128 * 64 * 2);
  ushort* Wlo3 = (ushort*)alloc(128 * 64 * 2);
  float* stats = (float*)alloc(3 * 128 * 4);

  hipMemsetAsync(deg, 0, (size_t)(n + 4) * 4, stream);
  hipMemsetAsync(stats, 0, 3 * 128 * 4, stream);
  hipMemsetAsync(Ybf + (size_t)n * 64, 0, 128, stream);  // zero sentinel row

  const int cnt4 = (n + 4) * (ELLS / 4);
  ell_init<<<(cnt4 + 255) / 256, 256, 0, stream>>>((int4*)ell, n, cnt4);
  const int bps = 2048;
  ell_fill_sharded<<<16 * bps, 256, 0, stream>>>(ei, deg, ell, E, n, bps);
  prep_w<<<64, 256, 0, stream>>>(W1l, W1r, Whi1, Wlo1, 128);
  prep_w<<<32, 256, 0, stream>>>(W2l, W2r, Whi2, Wlo2, 64);
  prep_w<<<32, 256, 0, stream>>>(W3l, W3r, Whi3, Wlo3, 64);

  const int gTile = (n + 63) / 64;
  const int gGath = 2048;

  // ---- layer 1 (bias b1 folded into Yrbf in gemm epilogue)
  gemm_mfma<128, false, false><<<gTile, 256, 0, stream>>>(
      x, nullptr, nullptr, nullptr, b1, Whi1, Wlo1, Ybf, Yrbf, n);
  gather_combine<<<gGath, 256, 0, stream>>>(Ybf, Yrbf, ell, deg, Tbf,
                                            stats + 0, n);

  // ---- layer 2 (BN1 finalize + norm fused into GEMM A-loads; bias b2)
  gemm_mfma<64, true, true><<<gTile, 256, 0, stream>>>(
      Tbf, stats + 0, g1, be1, b2, Whi2, Wlo2, Ybf, Yrbf, n);
  gather_combine<<<gGath, 256, 0, stream>>>(Ybf, Yrbf, ell, deg, Tbf,
                                            stats + 128, n);

  // ---- layer 3 (bias b3)
  gemm_mfma<64, true, true><<<gTile, 256, 0, stream>>>(
      Tbf, stats + 128, g2, be2, b3, Whi3, Wlo3, Ybf, Yrbf, n);
  gather_combine<<<gGath, 256, 0, stream>>>(Ybf, Yrbf, ell, deg, Tbf,
                                            stats + 256, n);

  // ---- fusion MLP (BN3 finalize + norm fused in)
  fusion_fused<<<gTile, 256, 0, stream>>>(Tbf, stats + 256, g3, be3, xgb, Wf1,
                                          bf1, Wf2, bf2, out, n);
}

// Round 15
// 496.987 us; speedup vs baseline: 1.3322x; 1.3322x over previous
//
#include <hip/hip_runtime.h>

// ---------------------------------------------------------------------------
// HybridSAGEClassifier: 3x SAGEConv(mean) + BN + ReLU, then fusion MLP.
// R1: project-first (mean(x[src])@Wl == mean((x@Wl)[src])).
// R2: scatter-atomics -> CSR + register gather.
// R3: single-block scan -> 3-stage parallel scan.
// R4: register-blocked GEMM + norm/ReLU fused into consumers.
// R5: one-pass ELL; bf16 gather table.
// R6: MFMA 16x16x32_bf16, bf16x3 split (~fp32 accuracy).
// R7: gather: 4-node interleaved chains, 8-edge uint4 requests; Yr bf16.
// R8: ell_fill -> 16 temporally-sharded dst ranges (L2-resident writes).
// R9 FAILED: block-centric per-lane gather. R8 layout is right for this.
// R10: R8 gather + T in bf16 + XBF16 GEMM staging.
// R11: branch-free gather (sentinel row); bn_finalize fused into consumers.
// R12: gemm sX LDS had zero reuse -> direct global A-loads; ELL stride 48.
// R13 FAILED: column-phase gather doubled FETCH -> fetch granularity is one
//      full 128B row; R12 gather already line-optimal.
// R14 FAILED: __launch_bounds__(256,8) forced VGPR 68->32 -> accumulator
//      spill to scratch (WRITE 13.5->152MB) + LDS-RMW stats conflicts
//      (432k). Lesson: never force wave bound below true live-set.
// R15: R12 gather verbatim (register stats, no forced bound) + R14's one
//      good piece: bias folded into GEMM epilogue -> kills bc[8], natural
//      VGPR ~60 (under the 64 boundary) -> 8 waves/SIMD without spill.
// ---------------------------------------------------------------------------

typedef __attribute__((ext_vector_type(8))) short bf16x8;
typedef __attribute__((ext_vector_type(4))) float f32x4;

#define ELLS 48  // ELL row stride

__device__ __forceinline__ ushort f2bf(float f) {
  unsigned u = __float_as_uint(f);
  return (ushort)((u + 0x7fff + ((u >> 16) & 1)) >> 16);  // RNE
}
__device__ __forceinline__ float bf2f(ushort h) {
  return __uint_as_float((unsigned)h << 16);
}
__device__ __forceinline__ void unpack8(uint4 v, float* f) {
  f[0] = __uint_as_float(v.x << 16);
  f[1] = __uint_as_float(v.x & 0xffff0000u);
  f[2] = __uint_as_float(v.y << 16);
  f[3] = __uint_as_float(v.y & 0xffff0000u);
  f[4] = __uint_as_float(v.z << 16);
  f[5] = __uint_as_float(v.z & 0xffff0000u);
  f[6] = __uint_as_float(v.w << 16);
  f[7] = __uint_as_float(v.w & 0xffff0000u);
}

// ---- ELL init: fill with sentinel row index n ------------------------------

__global__ __launch_bounds__(256) void ell_init(int4* __restrict__ ell,
                                                int val, int cnt4) {
  int i = blockIdx.x * 256 + threadIdx.x;
  if (i < cnt4) ell[i] = make_int4(val, val, val, val);
}

// ---- ELL build: temporally sharded scatter (R8) ----------------------------

__global__ __launch_bounds__(256) void ell_fill_sharded(
    const int* __restrict__ ei, int* __restrict__ deg, int* __restrict__ ell,
    int E, int n, int bps) {
  const int shard = blockIdx.x / bps;      // 0..15
  const int bib = blockIdx.x % bps;        // block-in-shard
  const int chunk = n >> 4;                // n/16
  const int lo = shard * chunk;
  const int hi = (shard == 15) ? n : lo + chunk;
  for (int e = bib * 256 + threadIdx.x; e < E; e += bps * 256) {
    int d = ei[E + e];
    if (d >= lo && d < hi) {
      int s = ei[e];
      int pos = atomicAdd(&deg[d], 1);
      if (pos < ELLS) ell[(size_t)d * ELLS + pos] = s;
    }
  }
}

// ---- W prep: combined (Wl|Wr) -> col-major bf16 hi/lo ----------------------

__global__ void prep_w(const float* __restrict__ Wl,
                       const float* __restrict__ Wr, ushort* __restrict__ Whi,
                       ushort* __restrict__ Wlo, int din) {
  int i = blockIdx.x * blockDim.x + threadIdx.x;
  if (i >= 128 * din) return;
  int col = i / din, k = i % din;
  float v = (col < 64) ? Wl[(size_t)k * 64 + col]
                       : Wr[(size_t)k * 64 + (col - 64)];
  ushort h = f2bf(v);
  Whi[i] = h;
  Wlo[i] = f2bf(v - bf2f(h));
}

// ---- MFMA dual GEMM (direct global A-loads; bias folded into Yr) -----------
// [Ybf | Yrbf+bias] = f(X) @ [Wl | Wr]; f = BN(stats,g,be)+ReLU or identity.
template <int DIN, bool NORM, bool XBF16>
__global__ __launch_bounds__(256) void gemm_mfma(
    const void* __restrict__ Xv, const float* __restrict__ stats,
    const float* __restrict__ g, const float* __restrict__ be,
    const float* __restrict__ bias, const ushort* __restrict__ Whi,
    const ushort* __restrict__ Wlo, ushort* __restrict__ Ybf,
    ushort* __restrict__ Yrbf, int n) {
  constexpr int WS = 40;
  __shared__ ushort sW[2 * 128 * WS];
  __shared__ float sSS[128];
  __shared__ float sB[64];
  const int tid = threadIdx.x;
  const int w = tid >> 6;
  const int lane = tid & 63;
  const int m = lane & 15;
  const int quad = lane >> 4;
  const int row0 = blockIdx.x * 64;

  if (tid < 64) {
    sB[tid] = bias[tid];
    if (NORM) {
      float invn = 1.0f / (float)n;
      float mu = stats[tid] * invn;
      float var = fmaf(-mu, mu, stats[64 + tid] * invn);
      float sc = g[tid] * rsqrtf(var + 1e-5f);
      sSS[tid] = sc;
      sSS[64 + tid] = fmaf(-mu, sc, be[tid]);
    }
  }

  const int arow = min(row0 + w * 16 + m, n - 1);

  f32x4 acc[8];
#pragma unroll
  for (int t = 0; t < 8; t++) acc[t] = (f32x4){0.f, 0.f, 0.f, 0.f};

  for (int kc = 0; kc < DIN; kc += 32) {
    __syncthreads();  // prev sW reads done / sSS+sB ready (first iter)
    for (int i = tid; i < 512; i += 256) {
      int col = i >> 2;
      int k = (i & 3) * 8;
      *reinterpret_cast<uint4*>(sW + col * WS + k) =
          *reinterpret_cast<const uint4*>(Whi + (size_t)col * DIN + kc + k);
      *reinterpret_cast<uint4*>(sW + 128 * WS + col * WS + k) =
          *reinterpret_cast<const uint4*>(Wlo + (size_t)col * DIN + kc + k);
    }
    __syncthreads();

    const int kb = kc + quad * 8;
    float av[8];
    if (XBF16) {
      const ushort* X = (const ushort*)Xv;
      uint4 v = *reinterpret_cast<const uint4*>(X + (size_t)arow * DIN + kb);
      unpack8(v, av);
    } else {
      const float* X = (const float*)Xv;
      const float* ap = X + (size_t)arow * DIN + kb;
      float4 a0 = *reinterpret_cast<const float4*>(ap);
      float4 a1 = *reinterpret_cast<const float4*>(ap + 4);
      av[0] = a0.x; av[1] = a0.y; av[2] = a0.z; av[3] = a0.w;
      av[4] = a1.x; av[5] = a1.y; av[6] = a1.z; av[7] = a1.w;
    }
    if (NORM) {
#pragma unroll
      for (int j = 0; j < 8; j++)
        av[j] = fmaxf(fmaf(av[j], sSS[kb + j], sSS[64 + kb + j]), 0.f);
    }
    bf16x8 Ahi, Alo;
#pragma unroll
    for (int j = 0; j < 8; j++) {
      ushort h = f2bf(av[j]);
      Ahi[j] = (short)h;
      Alo[j] = (short)f2bf(av[j] - bf2f(h));
    }
#pragma unroll
    for (int t = 0; t < 8; t++) {
      bf16x8 Bhi =
          *reinterpret_cast<const bf16x8*>(sW + (t * 16 + m) * WS + quad * 8);
      bf16x8 Blo = *reinterpret_cast<const bf16x8*>(sW + 128 * WS +
                                                    (t * 16 + m) * WS +
                                                    quad * 8);
      acc[t] = __builtin_amdgcn_mfma_f32_16x16x32_bf16(Ahi, Bhi, acc[t], 0, 0, 0);
      acc[t] = __builtin_amdgcn_mfma_f32_16x16x32_bf16(Ahi, Blo, acc[t], 0, 0, 0);
      acc[t] = __builtin_amdgcn_mfma_f32_16x16x32_bf16(Alo, Bhi, acc[t], 0, 0, 0);
    }
  }

#pragma unroll
  for (int t = 0; t < 8; t++) {
    int col = t * 16 + m;
#pragma unroll
    for (int r = 0; r < 4; r++) {
      int grow = row0 + w * 16 + quad * 4 + r;
      if (grow < n) {
        float v = acc[t][r];
        if (t < 4) {
          Ybf[(size_t)grow * 64 + col] = f2bf(v);
        } else {
          Yrbf[(size_t)grow * 64 + (col - 64)] = f2bf(v + sB[col - 64]);
        }
      }
    }
  }
}

// ---- ELL gather (R12 structure; bias pre-folded; register stats) -----------
// grp=lane>>3 picks one of 8 edge slots; sub=lane&7 picks a col octet
// (uint4 = 8 bf16; 8 lanes cover the full 128B row = one fetch line).
// Branch-free via sentinel row n (zeroed). No forced wave bound (R14 lesson).
__global__ __launch_bounds__(256) void gather_combine(
    const ushort* __restrict__ Ybf, const ushort* __restrict__ Yrbf,
    const int* __restrict__ ell, const int* __restrict__ deg,
    ushort* __restrict__ Tbf, float* __restrict__ stats, int n) {
  const int lane = threadIdx.x & 63;
  const int w = threadIdx.x >> 6;
  const int grp = lane >> 3;
  const int sub = lane & 7;
  const int wid = blockIdx.x * 4 + w;
  const int nw = gridDim.x * 4;
  float ssum[8], ssq[8];
#pragma unroll
  for (int c = 0; c < 8; c++) ssum[c] = ssq[c] = 0.f;

  for (int base = wid * 4; base < n; base += nw * 4) {
    int4 dg4 = *reinterpret_cast<const int4*>(deg + base);  // deg padded +4
    int dg[4] = {dg4.x, dg4.y, dg4.z, dg4.w};
    int mx = 0;
#pragma unroll
    for (int j = 0; j < 4; j++) mx = max(mx, min(dg[j], ELLS));
    float a[4][8];
#pragma unroll
    for (int j = 0; j < 4; j++)
#pragma unroll
      for (int c = 0; c < 8; c++) a[j][c] = 0.f;

    for (int e0 = 0; e0 < mx; e0 += 8) {
      int idx = e0 + grp;
      int s0 = ell[(size_t)(base + 0) * ELLS + idx];
      int s1 = ell[(size_t)(base + 1) * ELLS + idx];
      int s2 = ell[(size_t)(base + 2) * ELLS + idx];
      int s3 = ell[(size_t)(base + 3) * ELLS + idx];
      uint4 v0 = *reinterpret_cast<const uint4*>(Ybf + (size_t)s0 * 64 + sub * 8);
      uint4 v1 = *reinterpret_cast<const uint4*>(Ybf + (size_t)s1 * 64 + sub * 8);
      uint4 v2 = *reinterpret_cast<const uint4*>(Ybf + (size_t)s2 * 64 + sub * 8);
      uint4 v3 = *reinterpret_cast<const uint4*>(Ybf + (size_t)s3 * 64 + sub * 8);
      float f[8];
      unpack8(v0, f);
#pragma unroll
      for (int c = 0; c < 8; c++) a[0][c] += f[c];
      unpack8(v1, f);
#pragma unroll
      for (int c = 0; c < 8; c++) a[1][c] += f[c];
      unpack8(v2, f);
#pragma unroll
      for (int c = 0; c < 8; c++) a[2][c] += f[c];
      unpack8(v3, f);
#pragma unroll
      for (int c = 0; c < 8; c++) a[3][c] += f[c];
    }
#pragma unroll
    for (int mmask = 8; mmask <= 32; mmask <<= 1)
#pragma unroll
      for (int j = 0; j < 4; j++)
#pragma unroll
        for (int c = 0; c < 8; c++)
          a[j][c] += __shfl_xor(a[j][c], mmask, 64);

    if (lane < 8) {  // grp == 0: finalize; lane sub owns cols sub*8..+7
#pragma unroll
      for (int j = 0; j < 4; j++) {
        int node = base + j;
        if (node >= n) continue;
        float iv = 1.0f / (float)max(dg[j], 1);
        uint4 yrv =
            *reinterpret_cast<const uint4*>(Yrbf + (size_t)node * 64 + sub * 8);
        float yr[8];
        unpack8(yrv, yr);
        float t[8];
#pragma unroll
        for (int c = 0; c < 8; c++) {
          t[c] = fmaf(a[j][c], iv, yr[c]);  // bias already in Yrbf
          ssum[c] += t[c];
          ssq[c] = fmaf(t[c], t[c], ssq[c]);
        }
        uint4 o;
        o.x = (uint)f2bf(t[0]) | ((uint)f2bf(t[1]) << 16);
        o.y = (uint)f2bf(t[2]) | ((uint)f2bf(t[3]) << 16);
        o.z = (uint)f2bf(t[4]) | ((uint)f2bf(t[5]) << 16);
        o.w = (uint)f2bf(t[6]) | ((uint)f2bf(t[7]) << 16);
        *reinterpret_cast<uint4*>(Tbf + (size_t)node * 64 + sub * 8) = o;
      }
    }
  }
  __shared__ float rS[4][64];
  __shared__ float rQ[4][64];
  if (lane < 8) {
#pragma unroll
    for (int c = 0; c < 8; c++) {
      rS[w][sub * 8 + c] = ssum[c];
      rQ[w][sub * 8 + c] = ssq[c];
    }
  }
  __syncthreads();
  if (threadIdx.x < 64) {
    int tc = threadIdx.x;
    float s = rS[0][tc] + rS[1][tc] + rS[2][tc] + rS[3][tc];
    float qq = rQ[0][tc] + rQ[1][tc] + rQ[2][tc] + rQ[3][tc];
    atomicAdd(&stats[tc], s);
    atomicAdd(&stats[64 + tc], qq);
  }
}

// ---- fusion MLP: layer-3 BN (from raw stats) + ReLU fused, T in bf16 -------

__global__ __launch_bounds__(256) void fusion_fused(
    const ushort* __restrict__ Tbf, const float* __restrict__ stats,
    const float* __restrict__ g, const float* __restrict__ be,
    const float* __restrict__ xgb, const float* __restrict__ Wf1,
    const float* __restrict__ bf1, const float* __restrict__ Wf2,
    const float* __restrict__ bf2, float* __restrict__ out, int n) {
  __shared__ float sH[64 * 64];
  __shared__ float sW1[65 * 64];
  __shared__ float sW2[64];
  __shared__ float sSS[128];
  const int tid = threadIdx.x;
  const int c = tid & 63;
  const int w = tid >> 6;
  const int row0 = blockIdx.x * 64;
  if (tid < 64) {
    float invn = 1.0f / (float)n;
    float mu = stats[tid] * invn;
    float var = fmaf(-mu, mu, stats[64 + tid] * invn);
    float sc = g[tid] * rsqrtf(var + 1e-5f);
    sSS[tid] = sc;
    sSS[64 + tid] = fmaf(-mu, sc, be[tid]);
  }
  for (int i = tid; i < 65 * 64; i += 256) sW1[i] = Wf1[i];
  if (tid < 64) sW2[tid] = Wf2[tid];
  __syncthreads();
  for (int i = tid; i < 512; i += 256) {
    int r = i >> 3;
    int k = (i & 7) * 8;
    int row = min(row0 + r, n - 1);
    uint4 v = *reinterpret_cast<const uint4*>(Tbf + (size_t)row * 64 + k);
    float f[8];
    unpack8(v, f);
#pragma unroll
    for (int j = 0; j < 8; j++)
      f[j] = fmaxf(fmaf(f[j], sSS[k + j], sSS[64 + k + j]), 0.f);
    *reinterpret_cast<float4*>(sH + r * 64 + k) =
        make_float4(f[0], f[1], f[2], f[3]);
    *reinterpret_cast<float4*>(sH + r * 64 + k + 4) =
        make_float4(f[4], f[5], f[6], f[7]);
  }
  __syncthreads();
  const float b1v = bf1[c];
  const float wx = sW1[64 * 64 + c];
  const float w2v = sW2[c];
  const float b2v = bf2[0];
  float acc[16];
#pragma unroll
  for (int r = 0; r < 16; r++) acc[r] = b1v;
  for (int kk = 0; kk < 64; kk += 4) {
    float4 hv[16];
#pragma unroll
    for (int r = 0; r < 16; r++)
      hv[r] = *reinterpret_cast<const float4*>(sH + (w * 16 + r) * 64 + kk);
    float w0 = sW1[(kk + 0) * 64 + c];
    float w1 = sW1[(kk + 1) * 64 + c];
    float w2 = sW1[(kk + 2) * 64 + c];
    float w3 = sW1[(kk + 3) * 64 + c];
#pragma unroll
    for (int r = 0; r < 16; r++) {
      acc[r] = fmaf(hv[r].x, w0, acc[r]);
      acc[r] = fmaf(hv[r].y, w1, acc[r]);
      acc[r] = fmaf(hv[r].z, w2, acc[r]);
      acc[r] = fmaf(hv[r].w, w3, acc[r]);
    }
  }
#pragma unroll
  for (int r = 0; r < 16; r++) {
    int row = row0 + w * 16 + r;
    float xv = (row < n) ? xgb[row] : 0.f;
    float z = fmaxf(fmaf(xv, wx, acc[r]), 0.f) * w2v;
#pragma unroll
    for (int off = 32; off > 0; off >>= 1) z += __shfl_xor(z, off, 64);
    if (row < n && c == 0) out[row] = z + b2v;
  }
}

// ---- launch ----------------------------------------------------------------

extern "C" void kernel_launch(void* const* d_in, const int* in_sizes, int n_in,
                              void* d_out, int out_size, void* d_ws,
                              size_t ws_size, hipStream_t stream) {
  const float* x = (const float*)d_in[0];
  const int* ei = (const int*)d_in[1];
  const float* xgb = (const float*)d_in[2];
  const float* W1l = (const float*)d_in[3];
  const float* b1 = (const float*)d_in[4];
  const float* W1r = (const float*)d_in[5];
  const float* g1 = (const float*)d_in[6];
  const float* be1 = (const float*)d_in[7];
  const float* W2l = (const float*)d_in[8];
  const float* b2 = (const float*)d_in[9];
  const float* W2r = (const float*)d_in[10];
  const float* g2 = (const float*)d_in[11];
  const float* be2 = (const float*)d_in[12];
  const float* W3l = (const float*)d_in[13];
  const float* b3 = (const float*)d_in[14];
  const float* W3r = (const float*)d_in[15];
  const float* g3 = (const float*)d_in[16];
  const float* be3 = (const float*)d_in[17];
  const float* Wf1 = (const float*)d_in[18];
  const float* bf1 = (const float*)d_in[19];
  const float* Wf2 = (const float*)d_in[20];
  const float* bf2 = (const float*)d_in[21];
  float* out = (float*)d_out;

  const int n = in_sizes[2];      // 100000
  const int E = in_sizes[1] / 2;  // 1200000

  char* w = (char*)d_ws;
  auto alloc = [&](size_t bytes) {
    void* p = (void*)w;
    w += (bytes + 255) & ~(size_t)255;
    return p;
  };
  int* deg = (int*)alloc((size_t)(n + 4) * 4);           // +4 pad for int4
  int* ell = (int*)alloc((size_t)(n + 4) * ELLS * 4);    // +4 pad rows
  ushort* Ybf = (ushort*)alloc((size_t)(n + 1) * 64 * 2);  // +1 zero row
  ushort* Yrbf = (ushort*)alloc((size_t)n * 64 * 2);
  ushort* Tbf = (ushort*)alloc((size_t)n * 64 * 2);
  ushort* Whi1 = (ushort*)alloc(128 * 128 * 2);
  ushort* Wlo1 = (ushort*)alloc(128 * 128 * 2);
  ushort* Whi2 = (ushort*)alloc(128 * 64 * 2);
  ushort* Wlo2 = (ushort*)alloc(128 * 64 * 2);
  ushort* Whi3 = (ushort*)alloc(128 * 64 * 2);
  ushort* Wlo3 = (ushort*)alloc(128 * 64 * 2);
  float* stats = (float*)alloc(3 * 128 * 4);

  hipMemsetAsync(deg, 0, (size_t)(n + 4) * 4, stream);
  hipMemsetAsync(stats, 0, 3 * 128 * 4, stream);
  hipMemsetAsync(Ybf + (size_t)n * 64, 0, 128, stream);  // zero sentinel row

  const int cnt4 = (n + 4) * (ELLS / 4);
  ell_init<<<(cnt4 + 255) / 256, 256, 0, stream>>>((int4*)ell, n, cnt4);
  const int bps = 2048;
  ell_fill_sharded<<<16 * bps, 256, 0, stream>>>(ei, deg, ell, E, n, bps);
  prep_w<<<64, 256, 0, stream>>>(W1l, W1r, Whi1, Wlo1, 128);
  prep_w<<<32, 256, 0, stream>>>(W2l, W2r, Whi2, Wlo2, 64);
  prep_w<<<32, 256, 0, stream>>>(W3l, W3r, Whi3, Wlo3, 64);

  const int gTile = (n + 63) / 64;
  const int gGath = 2048;

  // ---- layer 1 (bias b1 folded into Yrbf in gemm epilogue)
  gemm_mfma<128, false, false><<<gTile, 256, 0, stream>>>(
      x, nullptr, nullptr, nullptr, b1, Whi1, Wlo1, Ybf, Yrbf, n);
  gather_combine<<<gGath, 256, 0, stream>>>(Ybf, Yrbf, ell, deg, Tbf,
                                            stats + 0, n);

  // ---- layer 2 (BN1 finalize + norm fused into GEMM A-loads; bias b2)
  gemm_mfma<64, true, true><<<gTile, 256, 0, stream>>>(
      Tbf, stats + 0, g1, be1, b2, Whi2, Wlo2, Ybf, Yrbf, n);
  gather_combine<<<gGath, 256, 0, stream>>>(Ybf, Yrbf, ell, deg, Tbf,
                                            stats + 128, n);

  // ---- layer 3 (bias b3)
  gemm_mfma<64, true, true><<<gTile, 256, 0, stream>>>(
      Tbf, stats + 128, g2, be2, b3, Whi3, Wlo3, Ybf, Yrbf, n);
  gather_combine<<<gGath, 256, 0, stream>>>(Ybf, Yrbf, ell, deg, Tbf,
                                            stats + 256, n);

  // ---- fusion MLP (BN3 finalize + norm fused in)
  fusion_fused<<<gTile, 256, 0, stream>>>(Tbf, stats + 256, g3, be3, xgb, Wf1,
                                          bf1, Wf2, bf2, out, n);
}